// Round 1
// baseline (320.085 us; speedup 1.0000x reference)
//
#include <hip/hip_runtime.h>
#include <math.h>

#define NB 4
#define NN 4096
#define KSEL 204
#define NBINS 512
#define CANDN 256
#define QKSCALE 0.31622776601683794f

// workspace layout in floats
#define WS_Q 0
#define WS_KT (NB * NN * 10)       // 163840
#define WS_V (2 * NB * NN * 10)    // 327680
#define WS_LG (3 * NB * NN * 10)   // 491520  (+ NB*NN*2 = 32768)

#define SEQ_PER_BLOCK 16

// kT layout: [B][N/64][10][64]  -> index b*40960 + (n>>6)*640 + c*64 + (n&63)
// gives attn one base address + 10 imm-offset dwordx4 loads per key-group.

__global__ __launch_bounds__(256) void featqkv_kernel(
    const float* __restrict__ x,
    const float* __restrict__ w2, const float* __restrict__ b2,
    const float* __restrict__ w3, const float* __restrict__ b3,
    const float* __restrict__ w4, const float* __restrict__ b4,
    const float* __restrict__ w5, const float* __restrict__ b5,
    const float* __restrict__ w6, const float* __restrict__ b6,
    const float* __restrict__ w7, const float* __restrict__ b7,
    const float* __restrict__ wq, const float* __restrict__ bq,
    const float* __restrict__ wk, const float* __restrict__ bk,
    const float* __restrict__ wv, const float* __restrict__ bv,
    float* __restrict__ q_out, float* __restrict__ kT_out, float* __restrict__ v_out)
{
    __shared__ __align__(16) float xs[SEQ_PER_BLOCK * 360];
    __shared__ float wpad[14 * 105];   // zero-padded to 7 taps: [ch][c=15][j=7]
    __shared__ float bconv[14];
    __shared__ float wqkv[420];
    __shared__ float bqkv[30];
    __shared__ float feats[SEQ_PER_BLOCK * 14];

    const int t = threadIdx.x;
    const int g0 = blockIdx.x * SEQ_PER_BLOCK;

    // ---- stage x as float4 ----
    {
        const float4* xg4 = reinterpret_cast<const float4*>(x + (size_t)g0 * 360);
        float4* xs4 = reinterpret_cast<float4*>(xs);
        for (int i = t; i < SEQ_PER_BLOCK * 90; i += 256) xs4[i] = xg4[i];
    }

    // ---- stage conv weights, zero-padded to uniform 7 taps ----
    for (int i = t; i < 14 * 105; i += 256) {
        const int ch = i / 105;
        const int r = i - ch * 105;
        const int c = r / 7;
        const int j = r - (r / 7) * 7;
        float val = 0.f;
        if (ch < 3)       { if (j < 2) val = w2[ch * 30 + c * 2 + j]; }
        else if (ch < 6)  { if (j < 3) val = w3[(ch - 3) * 45 + c * 3 + j]; }
        else if (ch < 9)  { if (j < 4) val = w4[(ch - 6) * 60 + c * 4 + j]; }
        else if (ch < 11) { if (j < 5) val = w5[(ch - 9) * 75 + c * 5 + j]; }
        else if (ch < 13) { if (j < 6) val = w6[(ch - 11) * 90 + c * 6 + j]; }
        else              { val = w7[c * 7 + j]; }
        wpad[i] = val;
    }
    if (t < 3) bconv[t] = b2[t];
    else if (t < 6) bconv[t] = b3[t - 3];
    else if (t < 9) bconv[t] = b4[t - 6];
    else if (t < 11) bconv[t] = b5[t - 9];
    else if (t < 13) bconv[t] = b6[t - 11];
    else if (t == 13) bconv[t] = b7[0];
    for (int i = t; i < 140; i += 256) wqkv[i] = wq[i];
    for (int i = t; i < 140; i += 256) wqkv[140 + i] = wk[i];
    for (int i = t; i < 140; i += 256) wqkv[280 + i] = wv[i];
    if (t < 10) bqkv[t] = bq[t];
    else if (t < 20) bqkv[t] = bk[t - 10];
    else if (t < 30) bqkv[t] = bv[t - 20];
    __syncthreads();

    const int seq = t >> 4;
    const int wkr = t & 15;

    if (wkr < 14) {
        const int ch = wkr;
        int T;
        if (ch < 3) T = 23; else if (ch < 6) T = 22; else if (ch < 9) T = 21;
        else if (ch < 11) T = 20; else if (ch < 13) T = 19; else T = 18;

        float acc[23];
#pragma unroll
        for (int u = 0; u < 23; u++) acc[u] = 0.f;
        const float* xrow = &xs[seq * 360];
        const float* wrow = &wpad[ch * 105];
        for (int c = 0; c < 15; c++) {
            float xr[30];
            const float4* xp = reinterpret_cast<const float4*>(xrow + c * 24);
#pragma unroll
            for (int u4 = 0; u4 < 6; u4++) {
                const float4 xv = xp[u4];
                xr[u4 * 4 + 0] = xv.x; xr[u4 * 4 + 1] = xv.y;
                xr[u4 * 4 + 2] = xv.z; xr[u4 * 4 + 3] = xv.w;
            }
#pragma unroll
            for (int u = 24; u < 30; u++) xr[u] = 0.f;
#pragma unroll
            for (int j = 0; j < 7; j++) {
                const float wv_ = wrow[c * 7 + j];
#pragma unroll
                for (int tt = 0; tt < 23; tt++)
                    acc[tt] = fmaf(xr[tt + j], wv_, acc[tt]);
            }
        }
        float m = -3.0e38f;
#pragma unroll
        for (int tt = 0; tt < 23; tt++)
            if (tt < T) m = fmaxf(m, acc[tt]);
        feats[seq * 14 + ch] = fmaxf(m + bconv[ch], 0.f);
    }
    __syncthreads();

    const int g = g0 + seq;
    const int b_ = g >> 12;
    const int n_ = g & 4095;
    for (int o = wkr; o < 30; o += 16) {
        const int type = o / 10;
        const int comp = o % 10;
        const float* wrow = &wqkv[type * 140 + comp * 14];
        const float* frow = &feats[seq * 14];
        float a = bqkv[type * 10 + comp];
#pragma unroll
        for (int ii = 0; ii < 14; ii++) a = fmaf(frow[ii], wrow[ii], a);
        if (type == 0) q_out[(size_t)g * 10 + comp] = a;
        else if (type == 1)
            kT_out[(size_t)b_ * 40960 + (size_t)(n_ >> 6) * 640 + comp * 64 + (n_ & 63)] = a;
        else v_out[(size_t)g * 10 + comp] = a;
    }
}

__device__ __forceinline__ float dec_key(unsigned int k) {
    return (k & 0x80000000u) ? __uint_as_float(k ^ 0x80000000u)
                             : __uint_as_float(~k);
}
__device__ __forceinline__ unsigned int enc_key(float s) {
    unsigned int u = __float_as_uint(s);
    return (u & 0x80000000u) ? ~u : (u | 0x80000000u);
}

// 256 threads / 1 row per block. Scores in registers; linear-histogram rank.
__global__ __launch_bounds__(256, 8) void attn_kernel(
    const float* __restrict__ qbuf, const float* __restrict__ kTbuf,
    const float* __restrict__ vbuf,
    const float* __restrict__ w_attn, const float* __restrict__ b_attn,
    const float* __restrict__ w_mil, const float* __restrict__ b_mil,
    float* __restrict__ out_probs, float* __restrict__ logits)
{
    __shared__ unsigned int base_[NBINS];   // counts -> suffix-above (pristine)
    __shared__ unsigned int bc_[NBINS];     // mutable scatter counters
    __shared__ unsigned long long cand[CANDN];
    __shared__ float hpart[4], lpart[4], fpart[4];
    __shared__ unsigned int wtot[4];
    __shared__ float ctxp[40];
    __shared__ float ctx_sh[10];
    __shared__ float attn_sh[14];

    const int t = threadIdx.x;
    const int lane = t & 63;
    const int w = t >> 6;
    const int row = blockIdx.x;
    const int b_ = row >> 12;

    // ---- P1: scores (registers) + block min/max ----
    float qr[10];
    {
        const float* qp = qbuf + (size_t)row * 10;
#pragma unroll
        for (int c = 0; c < 10; c++) qr[c] = qp[c];
    }
    const float* kTb = kTbuf + (size_t)b_ * 40960;
    float sc[16];
    float vhi = -1e30f, vlo = 1e30f;
#pragma unroll
    for (int i = 0; i < 4; i++) {
        // key group: 64 consecutive keys live in [g][10][64]; this thread's 4 keys
        // are at (t&15)*4 within group i*16 + (t>>4). One base, 10 imm-offset loads.
        const float4* kp = reinterpret_cast<const float4*>(
            kTb + (size_t)(i * 16 + (t >> 4)) * 640 + (t & 15) * 4);
        float ax = 0.f, ay = 0.f, az = 0.f, aw = 0.f;
#pragma unroll
        for (int c = 0; c < 10; c++) {
            const float4 kv = kp[c * 16];
            ax = fmaf(qr[c], kv.x, ax);
            ay = fmaf(qr[c], kv.y, ay);
            az = fmaf(qr[c], kv.z, az);
            aw = fmaf(qr[c], kv.w, aw);
        }
        sc[i * 4 + 0] = ax; sc[i * 4 + 1] = ay;
        sc[i * 4 + 2] = az; sc[i * 4 + 3] = aw;
        vhi = fmaxf(vhi, fmaxf(fmaxf(ax, ay), fmaxf(az, aw)));
        vlo = fminf(vlo, fminf(fminf(ax, ay), fminf(az, aw)));
    }
#pragma unroll
    for (int off = 32; off > 0; off >>= 1) {
        vhi = fmaxf(vhi, __shfl_xor(vhi, off));
        vlo = fminf(vlo, __shfl_xor(vlo, off));
    }
    if (lane == 0) { hpart[w] = vhi; lpart[w] = vlo; }
    // zero hist + cand under same barrier
    base_[2 * t] = 0u; base_[2 * t + 1] = 0u;
    cand[t] = 0ULL;
    __syncthreads();
    const float hi = fmaxf(fmaxf(hpart[0], hpart[1]), fmaxf(hpart[2], hpart[3]));
    const float lo = fminf(fminf(lpart[0], lpart[1]), fminf(lpart[2], lpart[3]));
    const bool degen = (hi <= lo);

    float pv = 0.f;
    int jj = 0, p = KSEL;
    bool selected = false;
    const float smax = hi * QKSCALE;

    if (!degen) {
        const float scale = (float)(NBINS - 1) / (hi - lo);

        // ---- P2: 512-bin linear histogram ----
#pragma unroll
        for (int i = 0; i < 16; i++) {
            const int bin = (int)fminf((sc[i] - lo) * scale, (float)(NBINS - 1));
            atomicAdd(&base_[bin], 1u);
        }
        __syncthreads();

        // ---- P3: suffix scan (2 bins/thread) -> base (pristine) + bc (mutable) ----
        {
            const unsigned int c0 = base_[2 * t];
            const unsigned int c1 = base_[2 * t + 1];
            const unsigned int T_ = c0 + c1;
            unsigned int acc = T_;
#pragma unroll
            for (int off = 1; off < 64; off <<= 1) {
                unsigned int o = __shfl_down(acc, off);
                if (lane + off < 64) acc += o;
            }
            if (lane == 0) wtot[w] = acc;
            __syncthreads();
            unsigned int tail = 0u;
#pragma unroll
            for (int w2 = 1; w2 < 4; w2++) if (w2 > w) tail += wtot[w2];
            const unsigned int A = (acc - T_) + tail;   // keys in bins > 2t+1
            base_[2 * t + 1] = A;
            base_[2 * t] = A + c1;
            bc_[2 * t + 1] = A;
            bc_[2 * t] = A + c1;
        }
        __syncthreads();

        // ---- P4: scatter candidate keys (bins whose base < KSEL) ----
#pragma unroll
        for (int i = 0; i < 16; i++) {
            const int bin = (int)fminf((sc[i] - lo) * scale, (float)(NBINS - 1));
            const unsigned int bs = base_[bin];
            if (bs < KSEL) {
                const unsigned int pos = atomicAdd(&bc_[bin], 1u);
                if (pos < CANDN) {
                    const int j = (i >> 2) * 1024 + t * 4 + (i & 3);
                    cand[pos] = (((unsigned long long)enc_key(sc[i])) << 16)
                              | (unsigned long long)(4095 - j);
                }
            }
        }
        __syncthreads();

        // ---- P5: within-bin rank -> exact sorted position ----
        const unsigned long long mine = cand[t];
        if (mine != 0ULL) {
            const float s = dec_key((unsigned int)(mine >> 16));
            const int bin = (int)fminf((s - lo) * scale, (float)(NBINS - 1));
            const unsigned int bs = base_[bin];
            // bin's keys occupy [base[bin], base[bin-1])
            unsigned int e2 = (bin > 0) ? base_[bin - 1] : 4096u;
            if (e2 > CANDN) e2 = CANDN;
            unsigned int rank = 0;
            for (unsigned int s2 = bs; s2 < e2; s2++)
                rank += (cand[s2] > mine) ? 1u : 0u;
            const unsigned int pp = bs + rank;
            if (pp < KSEL) {
                selected = true;
                p = (int)pp;
                jj = 4095 - (int)(mine & 0xFFFFu);
                pv = expf(s * QKSCALE - smax);
            }
        }
    } else {
        // all scores equal: top-K = lowest indices, uniform softmax
        if (t < KSEL) {
            selected = true;
            p = t;
            jj = t;
            pv = 1.f;
        }
    }

    // ---- P6: softmax denom ----
    float dsum = pv;
#pragma unroll
    for (int off = 32; off > 0; off >>= 1) dsum += __shfl_xor(dsum, off);
    if (lane == 0) fpart[w] = dsum;
    __syncthreads();
    const float inv = 1.f / (fpart[0] + fpart[1] + fpart[2] + fpart[3]);

    // ---- P7: probs out + ctx ----
    float cx0 = 0.f, cx1 = 0.f, cx2 = 0.f, cx3 = 0.f, cx4 = 0.f;
    float cx5 = 0.f, cx6 = 0.f, cx7 = 0.f, cx8 = 0.f, cx9 = 0.f;
    if (selected) {
        const float pn = pv * inv;
        out_probs[(size_t)row * KSEL + p] = pn;
        const float* vr = vbuf + ((size_t)b_ * NN + (size_t)jj) * 10;
        const float2 v01 = reinterpret_cast<const float2*>(vr)[0];
        const float2 v23 = reinterpret_cast<const float2*>(vr)[1];
        const float2 v45 = reinterpret_cast<const float2*>(vr)[2];
        const float2 v67 = reinterpret_cast<const float2*>(vr)[3];
        const float2 v89 = reinterpret_cast<const float2*>(vr)[4];
        cx0 = pn * v01.x; cx1 = pn * v01.y;
        cx2 = pn * v23.x; cx3 = pn * v23.y;
        cx4 = pn * v45.x; cx5 = pn * v45.y;
        cx6 = pn * v67.x; cx7 = pn * v67.y;
        cx8 = pn * v89.x; cx9 = pn * v89.y;
    }
#pragma unroll
    for (int off = 32; off > 0; off >>= 1) {
        cx0 += __shfl_xor(cx0, off); cx1 += __shfl_xor(cx1, off);
        cx2 += __shfl_xor(cx2, off); cx3 += __shfl_xor(cx3, off);
        cx4 += __shfl_xor(cx4, off); cx5 += __shfl_xor(cx5, off);
        cx6 += __shfl_xor(cx6, off); cx7 += __shfl_xor(cx7, off);
        cx8 += __shfl_xor(cx8, off); cx9 += __shfl_xor(cx9, off);
    }
    if (lane == 0) {
        ctxp[w * 10 + 0] = cx0; ctxp[w * 10 + 1] = cx1; ctxp[w * 10 + 2] = cx2;
        ctxp[w * 10 + 3] = cx3; ctxp[w * 10 + 4] = cx4; ctxp[w * 10 + 5] = cx5;
        ctxp[w * 10 + 6] = cx6; ctxp[w * 10 + 7] = cx7; ctxp[w * 10 + 8] = cx8;
        ctxp[w * 10 + 9] = cx9;
    }
    __syncthreads();
    if (t < 10) ctx_sh[t] = ctxp[t] + ctxp[10 + t] + ctxp[20 + t] + ctxp[30 + t];
    __syncthreads();

    // ---- P8: attn projection + mil logits ----
    if (t < 14) {
        float a = b_attn[t];
#pragma unroll
        for (int d = 0; d < 10; d++) a = fmaf(ctx_sh[d], w_attn[t * 10 + d], a);
        attn_sh[t] = a;
    }
    __syncthreads();
    if (t < 2) {
        float lg = b_mil[t];
#pragma unroll
        for (int ii = 0; ii < 14; ii++) lg = fmaf(attn_sh[ii], w_mil[t * 14 + ii], lg);
        logits[(size_t)row * 2 + t] = lg;
    }
}

__global__ __launch_bounds__(256) void pool_kernel(
    const float* __restrict__ logits, float* __restrict__ out)
{
    __shared__ float red[256];
    const int t = threadIdx.x;
    const int bc = blockIdx.x;
    const int b_ = bc >> 1;
    const int c_ = bc & 1;
    float a = 0.f;
    for (int n2 = t; n2 < NN; n2 += 256)
        a += logits[((size_t)b_ * NN + n2) * 2 + c_];
    red[t] = a;
    __syncthreads();
    for (int off = 128; off > 0; off >>= 1) {
        if (t < off) red[t] += red[t + off];
        __syncthreads();
    }
    if (t == 0) out[bc] = red[0] * (1.f / 4096.f);
}

extern "C" void kernel_launch(void* const* d_in, const int* in_sizes, int n_in,
                              void* d_out, int out_size, void* d_ws, size_t ws_size,
                              hipStream_t stream) {
    const float* x  = (const float*)d_in[0];
    const float* w2 = (const float*)d_in[1];  const float* b2 = (const float*)d_in[2];
    const float* w3 = (const float*)d_in[3];  const float* b3 = (const float*)d_in[4];
    const float* w4 = (const float*)d_in[5];  const float* b4 = (const float*)d_in[6];
    const float* w5 = (const float*)d_in[7];  const float* b5 = (const float*)d_in[8];
    const float* w6 = (const float*)d_in[9];  const float* b6 = (const float*)d_in[10];
    const float* w7 = (const float*)d_in[11]; const float* b7 = (const float*)d_in[12];
    const float* wq = (const float*)d_in[13]; const float* bq = (const float*)d_in[14];
    const float* wk = (const float*)d_in[15]; const float* bk = (const float*)d_in[16];
    const float* wv = (const float*)d_in[17]; const float* bv = (const float*)d_in[18];
    const float* wat = (const float*)d_in[19]; const float* bat = (const float*)d_in[20];
    const float* wm = (const float*)d_in[21];  const float* bm = (const float*)d_in[22];

    float* ws = (float*)d_ws;
    float* qb = ws + WS_Q;
    float* kT = ws + WS_KT;
    float* vb = ws + WS_V;
    float* lg = ws + WS_LG;
    float* out = (float*)d_out;

    hipLaunchKernelGGL(featqkv_kernel, dim3(NB * NN / SEQ_PER_BLOCK), dim3(256), 0, stream,
                       x, w2, b2, w3, b3, w4, b4, w5, b5, w6, b6, w7, b7,
                       wq, bq, wk, bk, wv, bv, qb, kT, vb);
    hipLaunchKernelGGL(attn_kernel, dim3(NB * NN), dim3(256), 0, stream,
                       qb, kT, vb, wat, bat, wm, bm, out + 8, lg);
    hipLaunchKernelGGL(pool_kernel, dim3(8), dim3(256), 0, stream, lg, out);
}

// Round 4
// 278.998 us; speedup vs baseline: 1.1473x; 1.1473x over previous
//
#include <hip/hip_runtime.h>
#include <math.h>

#define NB 4
#define NN 4096
#define KSEL 204
#define NBINS 512
#define CANDN 256
#define QKSCALE 0.31622776601683794f

// workspace layout in floats
#define WS_Q 0
#define WS_KT (NB * NN * 10)       // 163840
#define WS_V (2 * NB * NN * 10)    // 327680
#define WS_LG (3 * NB * NN * 10)   // 491520  (+ NB*NN*2 = 32768)

#define SEQ_PER_BLOCK 16

// kT layout: [B][10][N] row-major (REVERTED to round-0: the [B][N/64][10][64]
// variant broke L2 write-combining of out_probs -> 14x WRITE_SIZE).

__global__ __launch_bounds__(256) void featqkv_kernel(
    const float* __restrict__ x,
    const float* __restrict__ w2, const float* __restrict__ b2,
    const float* __restrict__ w3, const float* __restrict__ b3,
    const float* __restrict__ w4, const float* __restrict__ b4,
    const float* __restrict__ w5, const float* __restrict__ b5,
    const float* __restrict__ w6, const float* __restrict__ b6,
    const float* __restrict__ w7, const float* __restrict__ b7,
    const float* __restrict__ wq, const float* __restrict__ bq,
    const float* __restrict__ wk, const float* __restrict__ bk,
    const float* __restrict__ wv, const float* __restrict__ bv,
    float* __restrict__ q_out, float* __restrict__ kT_out, float* __restrict__ v_out)
{
    __shared__ __align__(16) float xs[SEQ_PER_BLOCK * 360];
    __shared__ float wpad[14 * 105];   // zero-padded to 7 taps: [ch][c=15][j=7]
    __shared__ float bconv[14];
    __shared__ float wqkv[420];
    __shared__ float bqkv[30];
    __shared__ float feats[SEQ_PER_BLOCK * 14];

    const int t = threadIdx.x;
    const int g0 = blockIdx.x * SEQ_PER_BLOCK;

    // ---- stage x as float4 ----
    {
        const float4* xg4 = reinterpret_cast<const float4*>(x + (size_t)g0 * 360);
        float4* xs4 = reinterpret_cast<float4*>(xs);
        for (int i = t; i < SEQ_PER_BLOCK * 90; i += 256) xs4[i] = xg4[i];
    }

    // ---- stage conv weights, zero-padded to uniform 7 taps ----
    for (int i = t; i < 14 * 105; i += 256) {
        const int ch = i / 105;
        const int r = i - ch * 105;
        const int c = r / 7;
        const int j = r - (r / 7) * 7;
        float val = 0.f;
        if (ch < 3)       { if (j < 2) val = w2[ch * 30 + c * 2 + j]; }
        else if (ch < 6)  { if (j < 3) val = w3[(ch - 3) * 45 + c * 3 + j]; }
        else if (ch < 9)  { if (j < 4) val = w4[(ch - 6) * 60 + c * 4 + j]; }
        else if (ch < 11) { if (j < 5) val = w5[(ch - 9) * 75 + c * 5 + j]; }
        else if (ch < 13) { if (j < 6) val = w6[(ch - 11) * 90 + c * 6 + j]; }
        else              { val = w7[c * 7 + j]; }
        wpad[i] = val;
    }
    if (t < 3) bconv[t] = b2[t];
    else if (t < 6) bconv[t] = b3[t - 3];
    else if (t < 9) bconv[t] = b4[t - 6];
    else if (t < 11) bconv[t] = b5[t - 9];
    else if (t < 13) bconv[t] = b6[t - 11];
    else if (t == 13) bconv[t] = b7[0];
    for (int i = t; i < 140; i += 256) wqkv[i] = wq[i];
    for (int i = t; i < 140; i += 256) wqkv[140 + i] = wk[i];
    for (int i = t; i < 140; i += 256) wqkv[280 + i] = wv[i];
    if (t < 10) bqkv[t] = bq[t];
    else if (t < 20) bqkv[t] = bk[t - 10];
    else if (t < 30) bqkv[t] = bv[t - 20];
    __syncthreads();

    const int seq = t >> 4;
    const int wkr = t & 15;

    if (wkr < 14) {
        const int ch = wkr;
        int T;
        if (ch < 3) T = 23; else if (ch < 6) T = 22; else if (ch < 9) T = 21;
        else if (ch < 11) T = 20; else if (ch < 13) T = 19; else T = 18;

        float acc[23];
#pragma unroll
        for (int u = 0; u < 23; u++) acc[u] = 0.f;
        const float* xrow = &xs[seq * 360];
        const float* wrow = &wpad[ch * 105];
        for (int c = 0; c < 15; c++) {
            float xr[30];
            const float4* xp = reinterpret_cast<const float4*>(xrow + c * 24);
#pragma unroll
            for (int u4 = 0; u4 < 6; u4++) {
                const float4 xv = xp[u4];
                xr[u4 * 4 + 0] = xv.x; xr[u4 * 4 + 1] = xv.y;
                xr[u4 * 4 + 2] = xv.z; xr[u4 * 4 + 3] = xv.w;
            }
#pragma unroll
            for (int u = 24; u < 30; u++) xr[u] = 0.f;
#pragma unroll
            for (int j = 0; j < 7; j++) {
                const float wv_ = wrow[c * 7 + j];
#pragma unroll
                for (int tt = 0; tt < 23; tt++)
                    acc[tt] = fmaf(xr[tt + j], wv_, acc[tt]);
            }
        }
        float m = -3.0e38f;
#pragma unroll
        for (int tt = 0; tt < 23; tt++)
            if (tt < T) m = fmaxf(m, acc[tt]);
        feats[seq * 14 + ch] = fmaxf(m + bconv[ch], 0.f);
    }
    __syncthreads();

    const int g = g0 + seq;
    const int b_ = g >> 12;
    const int n_ = g & 4095;
    for (int o = wkr; o < 30; o += 16) {
        const int type = o / 10;
        const int comp = o % 10;
        const float* wrow = &wqkv[type * 140 + comp * 14];
        const float* frow = &feats[seq * 14];
        float a = bqkv[type * 10 + comp];
#pragma unroll
        for (int ii = 0; ii < 14; ii++) a = fmaf(frow[ii], wrow[ii], a);
        if (type == 0) q_out[(size_t)g * 10 + comp] = a;
        else if (type == 1) kT_out[((size_t)b_ * 10 + comp) * NN + n_] = a;
        else v_out[(size_t)g * 10 + comp] = a;
    }
}

__device__ __forceinline__ float dec_key(unsigned int k) {
    return (k & 0x80000000u) ? __uint_as_float(k ^ 0x80000000u)
                             : __uint_as_float(~k);
}
__device__ __forceinline__ unsigned int enc_key(float s) {
    unsigned int u = __float_as_uint(s);
    return (u & 0x80000000u) ? ~u : (u | 0x80000000u);
}

// 256 threads / TWO rows per block (same batch -> shared kT loads).
// Scores in registers; linear-histogram rank, per-row state duplicated
// with compile-time indices only.
__global__ __launch_bounds__(256, 4) void attn_kernel(
    const float* __restrict__ qbuf, const float* __restrict__ kTbuf,
    const float* __restrict__ vbuf,
    const float* __restrict__ w_attn, const float* __restrict__ b_attn,
    const float* __restrict__ w_mil, const float* __restrict__ b_mil,
    float* __restrict__ out_probs, float* __restrict__ logits)
{
    __shared__ unsigned int base_[2][NBINS];   // counts -> suffix-above (pristine)
    __shared__ unsigned int bc_[2][NBINS];     // mutable scatter counters
    __shared__ unsigned long long cand[2][CANDN];
    __shared__ float hpart[2][4], lpart[2][4], fpart[2][4];
    __shared__ unsigned int wtot[2][4];
    __shared__ float ctxp[2][40];
    __shared__ float ctx_sh[2][10];
    __shared__ float attn_sh[2][14];

    const int t = threadIdx.x;
    const int lane = t & 63;
    const int w = t >> 6;
    const int r0 = blockIdx.x * 2;          // rows r0, r0+1 share a batch
    const int b_ = r0 >> 12;

    // ---- P1: scores for both rows with SHARED kT loads ----
    float qr[2][10];
    {
        const float4* qp4 = reinterpret_cast<const float4*>(qbuf + (size_t)r0 * 10);
        const float4 a = qp4[0], b = qp4[1], c = qp4[2], d = qp4[3], e = qp4[4];
        qr[0][0] = a.x; qr[0][1] = a.y; qr[0][2] = a.z; qr[0][3] = a.w;
        qr[0][4] = b.x; qr[0][5] = b.y; qr[0][6] = b.z; qr[0][7] = b.w;
        qr[0][8] = c.x; qr[0][9] = c.y;
        qr[1][0] = c.z; qr[1][1] = c.w;
        qr[1][2] = d.x; qr[1][3] = d.y; qr[1][4] = d.z; qr[1][5] = d.w;
        qr[1][6] = e.x; qr[1][7] = e.y; qr[1][8] = e.z; qr[1][9] = e.w;
    }
    const float* kTb = kTbuf + (size_t)b_ * 10 * NN;
    float sc[2][16];
    float vhi[2], vlo[2];
#pragma unroll
    for (int rr = 0; rr < 2; rr++) { vhi[rr] = -1e30f; vlo[rr] = 1e30f; }
#pragma unroll
    for (int i = 0; i < 4; i++) {
        float a0x = 0.f, a0y = 0.f, a0z = 0.f, a0w = 0.f;
        float a1x = 0.f, a1y = 0.f, a1z = 0.f, a1w = 0.f;
#pragma unroll
        for (int c = 0; c < 10; c++) {
            const float4 kv = reinterpret_cast<const float4*>(kTb + c * NN)[i * 256 + t];
            a0x = fmaf(qr[0][c], kv.x, a0x);
            a0y = fmaf(qr[0][c], kv.y, a0y);
            a0z = fmaf(qr[0][c], kv.z, a0z);
            a0w = fmaf(qr[0][c], kv.w, a0w);
            a1x = fmaf(qr[1][c], kv.x, a1x);
            a1y = fmaf(qr[1][c], kv.y, a1y);
            a1z = fmaf(qr[1][c], kv.z, a1z);
            a1w = fmaf(qr[1][c], kv.w, a1w);
        }
        sc[0][i * 4 + 0] = a0x; sc[0][i * 4 + 1] = a0y;
        sc[0][i * 4 + 2] = a0z; sc[0][i * 4 + 3] = a0w;
        sc[1][i * 4 + 0] = a1x; sc[1][i * 4 + 1] = a1y;
        sc[1][i * 4 + 2] = a1z; sc[1][i * 4 + 3] = a1w;
        vhi[0] = fmaxf(vhi[0], fmaxf(fmaxf(a0x, a0y), fmaxf(a0z, a0w)));
        vlo[0] = fminf(vlo[0], fminf(fminf(a0x, a0y), fminf(a0z, a0w)));
        vhi[1] = fmaxf(vhi[1], fmaxf(fmaxf(a1x, a1y), fmaxf(a1z, a1w)));
        vlo[1] = fminf(vlo[1], fminf(fminf(a1x, a1y), fminf(a1z, a1w)));
    }
#pragma unroll
    for (int off = 32; off > 0; off >>= 1) {
#pragma unroll
        for (int rr = 0; rr < 2; rr++) {
            vhi[rr] = fmaxf(vhi[rr], __shfl_xor(vhi[rr], off));
            vlo[rr] = fminf(vlo[rr], __shfl_xor(vlo[rr], off));
        }
    }
    if (lane == 0) {
#pragma unroll
        for (int rr = 0; rr < 2; rr++) { hpart[rr][w] = vhi[rr]; lpart[rr][w] = vlo[rr]; }
    }
    // zero hist + cand under same barrier
    {
        unsigned int* bz = &base_[0][0];
#pragma unroll
        for (int i = 0; i < 4; i++) bz[t + i * 256] = 0u;
        unsigned long long* cz = &cand[0][0];
        cz[t] = 0ULL; cz[t + 256] = 0ULL;
    }
    __syncthreads();

    float hi[2], lo[2], scale[2], smax[2];
    bool degen[2];
#pragma unroll
    for (int rr = 0; rr < 2; rr++) {
        hi[rr] = fmaxf(fmaxf(hpart[rr][0], hpart[rr][1]), fmaxf(hpart[rr][2], hpart[rr][3]));
        lo[rr] = fminf(fminf(lpart[rr][0], lpart[rr][1]), fminf(lpart[rr][2], lpart[rr][3]));
        degen[rr] = (hi[rr] <= lo[rr]);
        scale[rr] = degen[rr] ? 0.f : (float)(NBINS - 1) / (hi[rr] - lo[rr]);
        smax[rr] = hi[rr] * QKSCALE;
    }

    // ---- P2: 512-bin linear histogram (both rows) ----
#pragma unroll
    for (int rr = 0; rr < 2; rr++) {
        if (!degen[rr]) {
#pragma unroll
            for (int i = 0; i < 16; i++) {
                const int bin = (int)fminf((sc[rr][i] - lo[rr]) * scale[rr], (float)(NBINS - 1));
                atomicAdd(&base_[rr][bin], 1u);
            }
        }
    }
    __syncthreads();

    // ---- P3: suffix scan (2 bins/thread/row) ----
    unsigned int c1s[2], Ts[2], accs[2];
#pragma unroll
    for (int rr = 0; rr < 2; rr++) {
        const unsigned int c0 = base_[rr][2 * t];
        const unsigned int c1 = base_[rr][2 * t + 1];
        const unsigned int T_ = c0 + c1;
        unsigned int acc = T_;
#pragma unroll
        for (int off = 1; off < 64; off <<= 1) {
            unsigned int o = __shfl_down(acc, off);
            if (lane + off < 64) acc += o;
        }
        if (lane == 0) wtot[rr][w] = acc;
        c1s[rr] = c1; Ts[rr] = T_; accs[rr] = acc;
    }
    __syncthreads();
#pragma unroll
    for (int rr = 0; rr < 2; rr++) {
        unsigned int tail = 0u;
#pragma unroll
        for (int w2 = 1; w2 < 4; w2++) if (w2 > w) tail += wtot[rr][w2];
        const unsigned int A = (accs[rr] - Ts[rr]) + tail;   // keys in bins > 2t+1
        base_[rr][2 * t + 1] = A;
        base_[rr][2 * t] = A + c1s[rr];
        bc_[rr][2 * t + 1] = A;
        bc_[rr][2 * t] = A + c1s[rr];
    }
    __syncthreads();

    // ---- P4: scatter candidate keys (bins whose base < KSEL) ----
#pragma unroll
    for (int rr = 0; rr < 2; rr++) {
        if (!degen[rr]) {
#pragma unroll
            for (int i = 0; i < 16; i++) {
                const int bin = (int)fminf((sc[rr][i] - lo[rr]) * scale[rr], (float)(NBINS - 1));
                const unsigned int bs = base_[rr][bin];
                if (bs < KSEL) {
                    const unsigned int pos = atomicAdd(&bc_[rr][bin], 1u);
                    if (pos < CANDN) {
                        const int j = (i >> 2) * 1024 + t * 4 + (i & 3);
                        cand[rr][pos] = (((unsigned long long)enc_key(sc[rr][i])) << 16)
                                      | (unsigned long long)(4095 - j);
                    }
                }
            }
        }
    }
    __syncthreads();

    // ---- P5: within-bin rank -> exact sorted position ----
    float pv[2]; int jj[2], p[2]; bool selected[2];
#pragma unroll
    for (int rr = 0; rr < 2; rr++) {
        pv[rr] = 0.f; jj[rr] = 0; p[rr] = KSEL; selected[rr] = false;
        if (!degen[rr]) {
            const unsigned long long mine = cand[rr][t];
            if (mine != 0ULL) {
                const float s = dec_key((unsigned int)(mine >> 16));
                const int bin = (int)fminf((s - lo[rr]) * scale[rr], (float)(NBINS - 1));
                const unsigned int bs = base_[rr][bin];
                // bin's keys occupy [base[bin], base[bin-1])
                unsigned int e2 = (bin > 0) ? base_[rr][bin - 1] : 4096u;
                if (e2 > CANDN) e2 = CANDN;
                unsigned int rank = 0;
                for (unsigned int s2 = bs; s2 < e2; s2++)
                    rank += (cand[rr][s2] > mine) ? 1u : 0u;
                const unsigned int pp = bs + rank;
                if (pp < KSEL) {
                    selected[rr] = true;
                    p[rr] = (int)pp;
                    jj[rr] = 4095 - (int)(mine & 0xFFFFu);
                    pv[rr] = expf(s * QKSCALE - smax[rr]);
                }
            }
        } else {
            // all scores equal: top-K = lowest indices, uniform softmax
            if (t < KSEL) { selected[rr] = true; p[rr] = t; jj[rr] = t; pv[rr] = 1.f; }
        }
    }

    // ---- P6: softmax denom (both rows) ----
    float dsum[2];
#pragma unroll
    for (int rr = 0; rr < 2; rr++) dsum[rr] = pv[rr];
#pragma unroll
    for (int off = 32; off > 0; off >>= 1) {
#pragma unroll
        for (int rr = 0; rr < 2; rr++) dsum[rr] += __shfl_xor(dsum[rr], off);
    }
    if (lane == 0) {
#pragma unroll
        for (int rr = 0; rr < 2; rr++) fpart[rr][w] = dsum[rr];
    }
    __syncthreads();
    float inv[2];
#pragma unroll
    for (int rr = 0; rr < 2; rr++)
        inv[rr] = 1.f / (fpart[rr][0] + fpart[rr][1] + fpart[rr][2] + fpart[rr][3]);

    // ---- P7: probs out + ctx (both rows) ----
    float cx[2][10];
#pragma unroll
    for (int rr = 0; rr < 2; rr++)
#pragma unroll
        for (int d = 0; d < 10; d++) cx[rr][d] = 0.f;
#pragma unroll
    for (int rr = 0; rr < 2; rr++) {
        if (selected[rr]) {
            const float pn = pv[rr] * inv[rr];
            out_probs[(size_t)(r0 + rr) * KSEL + p[rr]] = pn;
            const float* vr = vbuf + ((size_t)b_ * NN + (size_t)jj[rr]) * 10;
            const float2 v01 = reinterpret_cast<const float2*>(vr)[0];
            const float2 v23 = reinterpret_cast<const float2*>(vr)[1];
            const float2 v45 = reinterpret_cast<const float2*>(vr)[2];
            const float2 v67 = reinterpret_cast<const float2*>(vr)[3];
            const float2 v89 = reinterpret_cast<const float2*>(vr)[4];
            cx[rr][0] = pn * v01.x; cx[rr][1] = pn * v01.y;
            cx[rr][2] = pn * v23.x; cx[rr][3] = pn * v23.y;
            cx[rr][4] = pn * v45.x; cx[rr][5] = pn * v45.y;
            cx[rr][6] = pn * v67.x; cx[rr][7] = pn * v67.y;
            cx[rr][8] = pn * v89.x; cx[rr][9] = pn * v89.y;
        }
    }
#pragma unroll
    for (int off = 32; off > 0; off >>= 1) {
#pragma unroll
        for (int rr = 0; rr < 2; rr++)
#pragma unroll
            for (int d = 0; d < 10; d++) cx[rr][d] += __shfl_xor(cx[rr][d], off);
    }
    if (lane == 0) {
#pragma unroll
        for (int rr = 0; rr < 2; rr++)
#pragma unroll
            for (int d = 0; d < 10; d++) ctxp[rr][w * 10 + d] = cx[rr][d];
    }
    __syncthreads();
    if (t < 10) ctx_sh[0][t] = ctxp[0][t] + ctxp[0][10 + t] + ctxp[0][20 + t] + ctxp[0][30 + t];
    else if (t >= 64 && t < 74) {
        const int d = t - 64;
        ctx_sh[1][d] = ctxp[1][d] + ctxp[1][10 + d] + ctxp[1][20 + d] + ctxp[1][30 + d];
    }
    __syncthreads();

    // ---- P8: attn projection + mil logits (row0 on wave0, row1 on wave1) ----
    if (t < 14) {
        float a = b_attn[t];
#pragma unroll
        for (int d = 0; d < 10; d++) a = fmaf(ctx_sh[0][d], w_attn[t * 10 + d], a);
        attn_sh[0][t] = a;
    } else if (t >= 64 && t < 78) {
        const int o = t - 64;
        float a = b_attn[o];
#pragma unroll
        for (int d = 0; d < 10; d++) a = fmaf(ctx_sh[1][d], w_attn[o * 10 + d], a);
        attn_sh[1][o] = a;
    }
    __syncthreads();
    if (t < 2) {
        float lg = b_mil[t];
#pragma unroll
        for (int ii = 0; ii < 14; ii++) lg = fmaf(attn_sh[0][ii], w_mil[t * 14 + ii], lg);
        logits[(size_t)r0 * 2 + t] = lg;
    } else if (t >= 64 && t < 66) {
        const int o = t - 64;
        float lg = b_mil[o];
#pragma unroll
        for (int ii = 0; ii < 14; ii++) lg = fmaf(attn_sh[1][ii], w_mil[o * 14 + ii], lg);
        logits[(size_t)(r0 + 1) * 2 + o] = lg;
    }
}

__global__ __launch_bounds__(256) void pool_kernel(
    const float* __restrict__ logits, float* __restrict__ out)
{
    __shared__ float red[256];
    const int t = threadIdx.x;
    const int bc = blockIdx.x;
    const int b_ = bc >> 1;
    const int c_ = bc & 1;
    float a = 0.f;
    for (int n2 = t; n2 < NN; n2 += 256)
        a += logits[((size_t)b_ * NN + n2) * 2 + c_];
    red[t] = a;
    __syncthreads();
    for (int off = 128; off > 0; off >>= 1) {
        if (t < off) red[t] += red[t + off];
        __syncthreads();
    }
    if (t == 0) out[bc] = red[0] * (1.f / 4096.f);
}

extern "C" void kernel_launch(void* const* d_in, const int* in_sizes, int n_in,
                              void* d_out, int out_size, void* d_ws, size_t ws_size,
                              hipStream_t stream) {
    const float* x  = (const float*)d_in[0];
    const float* w2 = (const float*)d_in[1];  const float* b2 = (const float*)d_in[2];
    const float* w3 = (const float*)d_in[3];  const float* b3 = (const float*)d_in[4];
    const float* w4 = (const float*)d_in[5];  const float* b4 = (const float*)d_in[6];
    const float* w5 = (const float*)d_in[7];  const float* b5 = (const float*)d_in[8];
    const float* w6 = (const float*)d_in[9];  const float* b6 = (const float*)d_in[10];
    const float* w7 = (const float*)d_in[11]; const float* b7 = (const float*)d_in[12];
    const float* wq = (const float*)d_in[13]; const float* bq = (const float*)d_in[14];
    const float* wk = (const float*)d_in[15]; const float* bk = (const float*)d_in[16];
    const float* wv = (const float*)d_in[17]; const float* bv = (const float*)d_in[18];
    const float* wat = (const float*)d_in[19]; const float* bat = (const float*)d_in[20];
    const float* wm = (const float*)d_in[21];  const float* bm = (const float*)d_in[22];

    float* ws = (float*)d_ws;
    float* qb = ws + WS_Q;
    float* kT = ws + WS_KT;
    float* vb = ws + WS_V;
    float* lg = ws + WS_LG;
    float* out = (float*)d_out;

    hipLaunchKernelGGL(featqkv_kernel, dim3(NB * NN / SEQ_PER_BLOCK), dim3(256), 0, stream,
                       x, w2, b2, w3, b3, w4, b4, w5, b5, w6, b6, w7, b7,
                       wq, bq, wk, bk, wv, bv, qb, kT, vb);
    hipLaunchKernelGGL(attn_kernel, dim3(NB * NN / 2), dim3(256), 0, stream,
                       qb, kT, vb, wat, bat, wm, bm, out + 8, lg);
    hipLaunchKernelGGL(pool_kernel, dim3(8), dim3(256), 0, stream, lg, out);
}